// Round 18
// baseline (1202.415 us; speedup 1.0000x reference)
//
#include <hip/hip_runtime.h>
#include <hip/hip_bf16.h>

// NodeModel: edge MLP ([x[col]||edge_attr] -> 64 relu -> 64 relu) -> scatter_mean
// over row -> node MLP ([x||agg||u[batch]] -> 64 relu -> 32).
// N=50000, E=1.6M, D_H=64.
//
// R18: two-level permute kills the meta-scatter line amplification that R17
// exposed (permute_edges: 12.8MB payload -> 101MB written, 117us):
//  - bin_edges: scatter 8B {eid, col|row<<16} into 196 coarse buckets
//    (row>>8; bucketstart = rowstart[b<<8] is FREE from the scan). Only 196
//    open dst lines (~25KB) -> L2 write-combines -> ~13MB effective.
//  - permute_gather_conv: reads bucket-grouped binned[] sequentially
//    (512-block grid-stride -> ~8-bucket / ~4MB active write window, L2
//    absorbed), places via cursor[row] atomics, writes sorted1[pos] (4B) +
//    gathered eattr[eid]->bf16->eattr_s[pos] (~1.0x amp; random reads hit
//    each line exactly once, R17-proven).
//  - edge_v2: prefetch next tile's 4B meta (+2 VGPR; NOT R6's 64B payload
//    trap) so the xbf gather issues at loop top. VGPR stays < 85 cap.
// Fallback (small ws) = R14 path.

typedef __attribute__((ext_vector_type(8))) short bf16x8;
typedef __attribute__((ext_vector_type(4))) float f32x4;

__device__ __forceinline__ unsigned short f2bf(float f) {
    __bf16 h = (__bf16)f;               // HW cvt (RNE)
    unsigned short u;
    __builtin_memcpy(&u, &h, 2);
    return u;
}
__device__ __forceinline__ bf16x8 pack8(const float4 a, const float4 b) {
    bf16x8 c;
    c[0] = (short)f2bf(a.x); c[1] = (short)f2bf(a.y);
    c[2] = (short)f2bf(a.z); c[3] = (short)f2bf(a.w);
    c[4] = (short)f2bf(b.x); c[5] = (short)f2bf(b.y);
    c[6] = (short)f2bf(b.z); c[7] = (short)f2bf(b.w);
    return c;
}

// ---------------- counting sort (+ x -> bf16 convert) ----------------

__global__ __launch_bounds__(256) void count_rows_convx(
    const int* __restrict__ erow, int* __restrict__ counts, int E,
    const float* __restrict__ x, unsigned short* __restrict__ xbf, int nx8)
{
    const int gid = blockIdx.x * blockDim.x + threadIdx.x;
    const int stride = gridDim.x * blockDim.x;
    for (int i = gid; i < nx8; i += stride) {
        const float4 a = ((const float4*)x)[2 * i];
        const float4 b = ((const float4*)x)[2 * i + 1];
        *(bf16x8*)(xbf + (size_t)i * 8) = pack8(a, b);
    }
    const int n4 = E >> 2;
    for (int i = gid; i < n4; i += stride) {
        const int4 r = ((const int4*)erow)[i];
        atomicAdd(&counts[r.x], 1);
        atomicAdd(&counts[r.y], 1);
        atomicAdd(&counts[r.z], 1);
        atomicAdd(&counts[r.w], 1);
    }
    for (int i = (n4 << 2) + gid; i < E; i += stride)
        atomicAdd(&counts[erow[i]], 1);
}

__global__ __launch_bounds__(256) void scan_blocks(
    const int* __restrict__ counts, int* __restrict__ excl,
    int* __restrict__ bsum, int N)
{
    __shared__ int tmp[256];
    const int t = threadIdx.x;
    const int i = blockIdx.x * 256 + t;
    const int v = (i < N) ? counts[i] : 0;
    tmp[t] = v; __syncthreads();
#pragma unroll
    for (int o = 1; o < 256; o <<= 1) {
        const int a = (t >= o) ? tmp[t - o] : 0;
        __syncthreads();
        tmp[t] += a;
        __syncthreads();
    }
    if (i < N) excl[i] = tmp[t] - v;
    if (t == 255) bsum[blockIdx.x] = tmp[t];
}

__global__ __launch_bounds__(256) void scan_bsum(int* __restrict__ bsum, int nb)
{
    __shared__ int tmp[256];
    const int t = threadIdx.x;
    const int v = (t < nb) ? bsum[t] : 0;
    tmp[t] = v; __syncthreads();
#pragma unroll
    for (int o = 1; o < 256; o <<= 1) {
        const int a = (t >= o) ? tmp[t - o] : 0;
        __syncthreads();
        tmp[t] += a;
        __syncthreads();
    }
    if (t < nb) bsum[t] = tmp[t] - v;   // exclusive
}

__global__ __launch_bounds__(256) void scan_add(
    int* __restrict__ rowstart, int* __restrict__ cursor,
    int* __restrict__ bucket_cursor,
    const int* __restrict__ bsum, int N, int E)
{
    const int i = blockIdx.x * 256 + threadIdx.x;
    if (i < N) {
        const int v = rowstart[i] + bsum[blockIdx.x];
        rowstart[i] = v;
        cursor[i]   = v;
        if ((i & 255) == 0) bucket_cursor[i >> 8] = v;  // bucketstart: FREE
    }
    if (i == 0) rowstart[N] = E;
}

// ---- pass A: bin edges into 196 coarse buckets (row>>8). Writes land on
// ---- ~196 open lines -> L2 write-combines -> ~payload-only traffic. ----
__global__ __launch_bounds__(256) void bin_edges(
    const int* __restrict__ erow, const int* __restrict__ ecol,
    int* __restrict__ bucket_cursor, int2* __restrict__ binned, int E)
{
    const int gid = blockIdx.x * blockDim.x + threadIdx.x;
    const int stride = gridDim.x * blockDim.x;
    for (int i = gid; i < E; i += stride) {
        const int r = erow[i];
        const int c = ecol[i];
        const int q = atomicAdd(&bucket_cursor[r >> 8], 1);
        binned[q] = int2{i, (int)((unsigned)c | ((unsigned)r << 16))};
    }
}

// ---- pass B: bucket-grouped input -> exact position via cursor[row];
// ---- writes stay within the active bucket window -> L2 absorbed. Also
// ---- gathers+converts eattr (random read, exactly once per line). ----
__global__ __launch_bounds__(256) void permute_gather_conv(
    const int2* __restrict__ binned, const float* __restrict__ eattr,
    int* __restrict__ cursor, int* __restrict__ sorted1,
    unsigned short* __restrict__ eattr_s, int E)
{
    const int gid = blockIdx.x * blockDim.x + threadIdx.x;
    const int stride = gridDim.x * blockDim.x;
    for (int p = gid; p < E; p += stride) {
        const int2 m2 = binned[p];
        const int row = (int)((unsigned)m2.y >> 16);
        const int pos = atomicAdd(&cursor[row], 1);
        sorted1[pos] = m2.y;
        const float4* src = (const float4*)(eattr + (size_t)m2.x * 32);
        unsigned short* dst = eattr_s + (size_t)pos * 32;
        float4 v0 = src[0], v1 = src[1], v2 = src[2], v3 = src[3];
        float4 v4 = src[4], v5 = src[5], v6 = src[6], v7 = src[7];
        *(bf16x8*)(dst +  0) = pack8(v0, v1);
        *(bf16x8*)(dst +  8) = pack8(v2, v3);
        *(bf16x8*)(dst + 16) = pack8(v4, v5);
        *(bf16x8*)(dst + 24) = pack8(v6, v7);
    }
}

// ---- fallback path: R14 permute (8B meta incl. eid) ----
__global__ __launch_bounds__(256) void permute_edges(
    const int* __restrict__ erow, const int* __restrict__ ecol,
    int* __restrict__ cursor, int2* __restrict__ sorted2, int E)
{
    const int gid = blockIdx.x * blockDim.x + threadIdx.x;
    const int stride = gridDim.x * blockDim.x;
    for (int i = gid; i < E; i += stride) {
        const int r = erow[i];
        const int pos = atomicAdd(&cursor[r], 1);
        sorted2[pos] = int2{i, (int)((unsigned)ecol[i] | ((unsigned)r << 16))};
    }
}

// ---------------- edge MLP v2: streamed bf16 eattr_s + bf16 x table ----------------

__global__ __launch_bounds__(256, 3) void edge_mlp_v2(
    const unsigned short* __restrict__ xbf,      // [N,32] bf16
    const int*            __restrict__ sorted1,  // [E] {col | row<<16}
    const unsigned short* __restrict__ eattr_s,  // [E,32] bf16, sorted order
    const float* __restrict__ W1a,  const float* __restrict__ b1a,
    const float* __restrict__ W1b,  const float* __restrict__ b1b,
    float* __restrict__ summed, int E)
{
    __shared__ __align__(16) unsigned short H2[4 * 16 * 64];  // 2KB/wave

    const int tid  = threadIdx.x;
    const int lane = tid & 63;
    const int wv   = tid >> 6;
    const int g    = lane >> 4;
    const int el   = lane & 15;

    unsigned short* const h2w = H2 + wv * (16 * 64);

    bf16x8 wa[4][2], wb[4][2];
    f32x4  bias1[4];
    float  bias2s[4];
#pragma unroll
    for (int mt = 0; mt < 4; ++mt) {
        const int o = mt * 16 + el;
#pragma unroll
        for (int ks = 0; ks < 2; ++ks) {
            bf16x8 ta, tb;
#pragma unroll
            for (int j = 0; j < 8; ++j) {
                const int k = ks * 32 + 8 * g + j;
                ta[j] = (short)f2bf(W1a[k * 64 + o]);
                tb[j] = (short)f2bf(W1b[k * 64 + o]);
            }
            wa[mt][ks] = ta;
            wb[mt][ks] = tb;
        }
#pragma unroll
        for (int r = 0; r < 4; ++r) bias1[mt][r] = b1a[mt * 16 + 4 * g + r];
        bias2s[mt] = b1b[o];
    }

    const int ntile = (E + 15) >> 4;
    const int wid   = blockIdx.x * 4 + wv;
    const int nw    = gridDim.x * 4;
    const int sw    = el & 7;

    // ---- meta prefetch (4B): m_cur holds tile t's meta on loop entry ----
    int m_cur;
    {
        const int e0 = (wid << 4) + el;
        m_cur = sorted1[(e0 < E) ? e0 : 0];
    }

    for (int t = wid; t < ntile; t += nw) {
        const int ebase = t << 4;
        const int e     = ebase + el;

        // decode with validity (LOGICAL shift — R15 lesson)
        const int m   = m_cur;
        const int row = (e < E) ? (int)((unsigned)m >> 16) : -1;
        const int col = (e < E) ? (m & 0xFFFF) : 0;

        // prefetch next tile's meta NOW (xbf gather below no longer waits)
        {
            const int e2 = ((t + nw) << 4) + el;
            m_cur = sorted1[(e2 < E) ? e2 : 0];
        }

        const int ee = (e < E) ? e : (E - 1);
        const bf16x8 bf0 = *(const bf16x8*)(xbf + (size_t)col * 32 + 8 * g);
        const bf16x8 bf1 = *(const bf16x8*)(eattr_s + (size_t)ee * 32 + 8 * g);

        f32x4 a0 = bias1[0], a1 = bias1[1], a2 = bias1[2], a3 = bias1[3];
        a0 = __builtin_amdgcn_mfma_f32_16x16x32_bf16(wa[0][0], bf0, a0, 0, 0, 0);
        a1 = __builtin_amdgcn_mfma_f32_16x16x32_bf16(wa[1][0], bf0, a1, 0, 0, 0);
        a2 = __builtin_amdgcn_mfma_f32_16x16x32_bf16(wa[2][0], bf0, a2, 0, 0, 0);
        a3 = __builtin_amdgcn_mfma_f32_16x16x32_bf16(wa[3][0], bf0, a3, 0, 0, 0);
        a0 = __builtin_amdgcn_mfma_f32_16x16x32_bf16(wa[0][1], bf1, a0, 0, 0, 0);
        a1 = __builtin_amdgcn_mfma_f32_16x16x32_bf16(wa[1][1], bf1, a1, 0, 0, 0);
        a2 = __builtin_amdgcn_mfma_f32_16x16x32_bf16(wa[2][1], bf1, a2, 0, 0, 0);
        a3 = __builtin_amdgcn_mfma_f32_16x16x32_bf16(wa[3][1], bf1, a3, 0, 0, 0);

        unsigned short* hrow = h2w + el * 64;
        {
            f32x4 accs[4] = {a0, a1, a2, a3};
#pragma unroll
            for (int mt = 0; mt < 4; ++mt) {
                unsigned short pk[4];
#pragma unroll
                for (int r = 0; r < 4; ++r) pk[r] = f2bf(fmaxf(accs[mt][r], 0.f));
                const int hid   = mt * 16 + 4 * g;
                const int chunk = hid >> 3;
                const int off   = hid & 7;
                *(uint2*)(hrow + ((chunk ^ sw) * 8 + off)) = *(uint2*)pk;
            }
        }

        const bf16x8 hb0 = *(const bf16x8*)(hrow + (((0 + g) ^ sw) * 8));
        const bf16x8 hb1 = *(const bf16x8*)(hrow + (((4 + g) ^ sw) * 8));
        f32x4 d0 = {bias2s[0], bias2s[0], bias2s[0], bias2s[0]};
        f32x4 d1 = {bias2s[1], bias2s[1], bias2s[1], bias2s[1]};
        f32x4 d2 = {bias2s[2], bias2s[2], bias2s[2], bias2s[2]};
        f32x4 d3 = {bias2s[3], bias2s[3], bias2s[3], bias2s[3]};
        d0 = __builtin_amdgcn_mfma_f32_16x16x32_bf16(hb0, wb[0][0], d0, 0, 0, 0);
        d1 = __builtin_amdgcn_mfma_f32_16x16x32_bf16(hb0, wb[1][0], d1, 0, 0, 0);
        d2 = __builtin_amdgcn_mfma_f32_16x16x32_bf16(hb0, wb[2][0], d2, 0, 0, 0);
        d3 = __builtin_amdgcn_mfma_f32_16x16x32_bf16(hb0, wb[3][0], d3, 0, 0, 0);
        d0 = __builtin_amdgcn_mfma_f32_16x16x32_bf16(hb1, wb[0][1], d0, 0, 0, 0);
        d1 = __builtin_amdgcn_mfma_f32_16x16x32_bf16(hb1, wb[1][1], d1, 0, 0, 0);
        d2 = __builtin_amdgcn_mfma_f32_16x16x32_bf16(hb1, wb[2][1], d2, 0, 0, 0);
        d3 = __builtin_amdgcn_mfma_f32_16x16x32_bf16(hb1, wb[3][1], d3, 0, 0, 0);

#pragma unroll
        for (int r = 0; r < 4; ++r) {
            d0[r] = fmaxf(d0[r], 0.f);
            d1[r] = fmaxf(d1[r], 0.f);
            d2[r] = fmaxf(d2[r], 0.f);
            d3[r] = fmaxf(d3[r], 0.f);
        }

        const int prevrow = __shfl(row, lane - 1);
        unsigned long long bmask =
            __ballot((g == 0) && (el > 0) && (row != prevrow));
        bmask = (bmask & 0xFFFEull) | 0x10000ull;

        int s = 0;
        while (s < 16) {
            const int e2 = s + 1 + (__ffsll(bmask >> (s + 1)) - 1);
            const int rowid = __shfl(row, s);
            if (rowid >= 0) {
                float s0 = 0.f, s1 = 0.f, s2v = 0.f, s3 = 0.f;
#pragma unroll
                for (int r = 0; r < 4; ++r) {
                    const int ej = 4 * g + r;
                    const bool in = (ej >= s) && (ej < e2);
                    s0  += in ? d0[r] : 0.f;
                    s1  += in ? d1[r] : 0.f;
                    s2v += in ? d2[r] : 0.f;
                    s3  += in ? d3[r] : 0.f;
                }
                s0  += __shfl_xor(s0, 16);  s0  += __shfl_xor(s0, 32);
                s1  += __shfl_xor(s1, 16);  s1  += __shfl_xor(s1, 32);
                s2v += __shfl_xor(s2v, 16); s2v += __shfl_xor(s2v, 32);
                s3  += __shfl_xor(s3, 16);  s3  += __shfl_xor(s3, 32);
                const float val = (g == 0) ? s0 : (g == 1) ? s1
                                : (g == 2) ? s2v : s3;
                unsafeAtomicAdd(&summed[(size_t)rowid * 64 + lane], val);
            }
            s = e2;
        }
    }
}

// ---------------- edge MLP fallback (R14: f32 gather via sorted2) ----------------

__global__ __launch_bounds__(256, 3) void edge_mlp_mfma(
    const float* __restrict__ x,
    const int2*  __restrict__ sorted2,
    const float* __restrict__ eattr,
    const float* __restrict__ W1a,  const float* __restrict__ b1a,
    const float* __restrict__ W1b,  const float* __restrict__ b1b,
    float* __restrict__ summed, int E)
{
    __shared__ __align__(16) unsigned short H2[4 * 16 * 64];
    const int tid  = threadIdx.x;
    const int lane = tid & 63;
    const int wv   = tid >> 6;
    const int g    = lane >> 4;
    const int el   = lane & 15;
    unsigned short* const h2w = H2 + wv * (16 * 64);

    bf16x8 wa[4][2], wb[4][2];
    f32x4  bias1[4];
    float  bias2s[4];
#pragma unroll
    for (int mt = 0; mt < 4; ++mt) {
        const int o = mt * 16 + el;
#pragma unroll
        for (int ks = 0; ks < 2; ++ks) {
            bf16x8 ta, tb;
#pragma unroll
            for (int j = 0; j < 8; ++j) {
                const int k = ks * 32 + 8 * g + j;
                ta[j] = (short)f2bf(W1a[k * 64 + o]);
                tb[j] = (short)f2bf(W1b[k * 64 + o]);
            }
            wa[mt][ks] = ta;
            wb[mt][ks] = tb;
        }
#pragma unroll
        for (int r = 0; r < 4; ++r) bias1[mt][r] = b1a[mt * 16 + 4 * g + r];
        bias2s[mt] = b1b[o];
    }

    const int ntile = (E + 15) >> 4;
    const int wid   = blockIdx.x * 4 + wv;
    const int nw    = gridDim.x * 4;
    const int sw    = el & 7;

    for (int t = wid; t < ntile; t += nw) {
        const int ebase = t << 4;
        int2 s2; int row;
        if (ebase + el < E) {
            s2 = sorted2[ebase + el];
            row = (int)((unsigned)s2.y >> 16);
        } else { s2 = int2{0, 0}; row = -1; }

        bf16x8 bf0, bf1;
        {
            const float4* xp = (const float4*)(x + (size_t)(s2.y & 0xFFFF) * 32 + 8 * g);
            const float4* ap = (const float4*)(eattr + (size_t)s2.x * 32 + 8 * g);
            bf0 = pack8(xp[0], xp[1]);
            bf1 = pack8(ap[0], ap[1]);
        }

        f32x4 a0 = bias1[0], a1 = bias1[1], a2 = bias1[2], a3 = bias1[3];
        a0 = __builtin_amdgcn_mfma_f32_16x16x32_bf16(wa[0][0], bf0, a0, 0, 0, 0);
        a1 = __builtin_amdgcn_mfma_f32_16x16x32_bf16(wa[1][0], bf0, a1, 0, 0, 0);
        a2 = __builtin_amdgcn_mfma_f32_16x16x32_bf16(wa[2][0], bf0, a2, 0, 0, 0);
        a3 = __builtin_amdgcn_mfma_f32_16x16x32_bf16(wa[3][0], bf0, a3, 0, 0, 0);
        a0 = __builtin_amdgcn_mfma_f32_16x16x32_bf16(wa[0][1], bf1, a0, 0, 0, 0);
        a1 = __builtin_amdgcn_mfma_f32_16x16x32_bf16(wa[1][1], bf1, a1, 0, 0, 0);
        a2 = __builtin_amdgcn_mfma_f32_16x16x32_bf16(wa[2][1], bf1, a2, 0, 0, 0);
        a3 = __builtin_amdgcn_mfma_f32_16x16x32_bf16(wa[3][1], bf1, a3, 0, 0, 0);

        unsigned short* hrow = h2w + el * 64;
        {
            f32x4 accs[4] = {a0, a1, a2, a3};
#pragma unroll
            for (int mt = 0; mt < 4; ++mt) {
                unsigned short pk[4];
#pragma unroll
                for (int r = 0; r < 4; ++r) pk[r] = f2bf(fmaxf(accs[mt][r], 0.f));
                const int hid   = mt * 16 + 4 * g;
                const int chunk = hid >> 3;
                const int off   = hid & 7;
                *(uint2*)(hrow + ((chunk ^ sw) * 8 + off)) = *(uint2*)pk;
            }
        }

        const bf16x8 hb0 = *(const bf16x8*)(hrow + (((0 + g) ^ sw) * 8));
        const bf16x8 hb1 = *(const bf16x8*)(hrow + (((4 + g) ^ sw) * 8));
        f32x4 d0 = {bias2s[0], bias2s[0], bias2s[0], bias2s[0]};
        f32x4 d1 = {bias2s[1], bias2s[1], bias2s[1], bias2s[1]};
        f32x4 d2 = {bias2s[2], bias2s[2], bias2s[2], bias2s[2]};
        f32x4 d3 = {bias2s[3], bias2s[3], bias2s[3], bias2s[3]};
        d0 = __builtin_amdgcn_mfma_f32_16x16x32_bf16(hb0, wb[0][0], d0, 0, 0, 0);
        d1 = __builtin_amdgcn_mfma_f32_16x16x32_bf16(hb0, wb[1][0], d1, 0, 0, 0);
        d2 = __builtin_amdgcn_mfma_f32_16x16x32_bf16(hb0, wb[2][0], d2, 0, 0, 0);
        d3 = __builtin_amdgcn_mfma_f32_16x16x32_bf16(hb0, wb[3][0], d3, 0, 0, 0);
        d0 = __builtin_amdgcn_mfma_f32_16x16x32_bf16(hb1, wb[0][1], d0, 0, 0, 0);
        d1 = __builtin_amdgcn_mfma_f32_16x16x32_bf16(hb1, wb[1][1], d1, 0, 0, 0);
        d2 = __builtin_amdgcn_mfma_f32_16x16x32_bf16(hb1, wb[2][1], d2, 0, 0, 0);
        d3 = __builtin_amdgcn_mfma_f32_16x16x32_bf16(hb1, wb[3][1], d3, 0, 0, 0);

#pragma unroll
        for (int r = 0; r < 4; ++r) {
            d0[r] = fmaxf(d0[r], 0.f);
            d1[r] = fmaxf(d1[r], 0.f);
            d2[r] = fmaxf(d2[r], 0.f);
            d3[r] = fmaxf(d3[r], 0.f);
        }

        const int prevrow = __shfl(row, lane - 1);
        unsigned long long bmask =
            __ballot((g == 0) && (el > 0) && (row != prevrow));
        bmask = (bmask & 0xFFFEull) | 0x10000ull;

        int s = 0;
        while (s < 16) {
            const int e = s + 1 + (__ffsll(bmask >> (s + 1)) - 1);
            const int rowid = __shfl(row, s);
            if (rowid >= 0) {
                float s0 = 0.f, s1 = 0.f, s2v = 0.f, s3 = 0.f;
#pragma unroll
                for (int r = 0; r < 4; ++r) {
                    const int ej = 4 * g + r;
                    const bool in = (ej >= s) && (ej < e);
                    s0  += in ? d0[r] : 0.f;
                    s1  += in ? d1[r] : 0.f;
                    s2v += in ? d2[r] : 0.f;
                    s3  += in ? d3[r] : 0.f;
                }
                s0  += __shfl_xor(s0, 16);  s0  += __shfl_xor(s0, 32);
                s1  += __shfl_xor(s1, 16);  s1  += __shfl_xor(s1, 32);
                s2v += __shfl_xor(s2v, 16); s2v += __shfl_xor(s2v, 32);
                s3  += __shfl_xor(s3, 16);  s3  += __shfl_xor(s3, 32);
                const float val = (g == 0) ? s0 : (g == 1) ? s1
                                : (g == 2) ? s2v : s3;
                unsafeAtomicAdd(&summed[(size_t)rowid * 64 + lane], val);
            }
            s = e;
        }
    }
}

// ---------------- node MLP via MFMA ----------------

__global__ __launch_bounds__(256, 2) void node_mlp_mfma(
    const float* __restrict__ x,        // [N,32]
    const float* __restrict__ summed,   // [N,64]
    const int*   __restrict__ rowstart, // [N+1]
    const float* __restrict__ u,        // [G,16]
    const int*   __restrict__ batch,    // [N]
    const float* __restrict__ W2a,      // [112,64]
    const float* __restrict__ b2a,      // [64]
    const float* __restrict__ W2b,      // [64,32]
    const float* __restrict__ b2b,      // [32]
    float* __restrict__ out,            // [N,32]
    int N)
{
    __shared__ __align__(16) unsigned short In[64 * 128];  // 16KB
    __shared__ __align__(16) unsigned short H[64 * 64];    // 8KB

    const int tid  = threadIdx.x;
    const int lane = tid & 63;
    const int wv   = tid >> 6;
    const int g    = lane >> 4;
    const int el   = lane & 15;

    bf16x8 wa[4][4];
    f32x4  bias1[4];
#pragma unroll
    for (int mt = 0; mt < 4; ++mt) {
        const int o = mt * 16 + el;
#pragma unroll
        for (int ks = 0; ks < 4; ++ks) {
            bf16x8 ta;
#pragma unroll
            for (int j = 0; j < 8; ++j) {
                const int k = ks * 32 + 8 * g + j;
                ta[j] = (k < 112) ? (short)f2bf(W2a[k * 64 + o]) : (short)0;
            }
            wa[mt][ks] = ta;
        }
#pragma unroll
        for (int r = 0; r < 4; ++r) bias1[mt][r] = b2a[mt * 16 + 4 * g + r];
    }
    bf16x8 wb[2][2];
    float  bias2s[2];
#pragma unroll
    for (int nt = 0; nt < 2; ++nt) {
        const int o = nt * 16 + el;
#pragma unroll
        for (int ks = 0; ks < 2; ++ks) {
            bf16x8 tb;
#pragma unroll
            for (int j = 0; j < 8; ++j) {
                const int k = ks * 32 + 8 * g + j;
                tb[j] = (short)f2bf(W2b[k * 32 + o]);
            }
            wb[nt][ks] = tb;
        }
        bias2s[nt] = b2b[o];
    }

    unsigned short* const inrow = In + (wv * 16) * 128;
    unsigned short* const hrow0 = H + (wv * 16) * 64;

    const int ntile = (N + 15) >> 4;
    const int wid   = blockIdx.x * 4 + wv;
    const int nw    = gridDim.x * 4;

    for (int t = wid; t < ntile; t += nw) {
        const int nbase = t << 4;
        {
            const int le = lane >> 2;
            const int p  = lane & 3;
            const int n  = nbase + le;
            float4 v[8];
            if (n < N) {
                if (p == 0) {
                    const float4* xp = (const float4*)(x + (size_t)n * 32);
#pragma unroll
                    for (int q = 0; q < 8; ++q) v[q] = xp[q];
                } else if (p < 3) {
                    const int cnt = rowstart[n + 1] - rowstart[n];
                    const float inv = 1.0f / fmaxf((float)cnt, 1.0f);
                    const float4* sp = (const float4*)(summed + (size_t)n * 64 + (p - 1) * 32);
#pragma unroll
                    for (int q = 0; q < 8; ++q) {
                        v[q] = sp[q];
                        v[q].x *= inv; v[q].y *= inv; v[q].z *= inv; v[q].w *= inv;
                    }
                } else {
                    const int gb = batch[n];
                    const float4* up = (const float4*)(u + (size_t)gb * 16);
#pragma unroll
                    for (int q = 0; q < 4; ++q) v[q] = up[q];
#pragma unroll
                    for (int q = 4; q < 8; ++q) v[q] = float4{0.f, 0.f, 0.f, 0.f};
                }
            } else {
#pragma unroll
                for (int q = 0; q < 8; ++q) v[q] = float4{0.f, 0.f, 0.f, 0.f};
            }
            const int sw = le & 7;
            unsigned short* row = inrow + le * 128;
#pragma unroll
            for (int q = 0; q < 4; ++q) {
                const int cc = 4 * p + q;
                const int ci = (cc & 8) | ((cc & 7) ^ sw);
                *(bf16x8*)(row + ci * 8) = pack8(v[2 * q], v[2 * q + 1]);
            }
        }

        const unsigned short* brow = inrow + el * 128;
        const int sw7 = el & 7;
        f32x4 a0 = bias1[0], a1 = bias1[1], a2 = bias1[2], a3 = bias1[3];
#pragma unroll
        for (int ks = 0; ks < 4; ++ks) {
            const int cc = ks * 4 + g;
            const int ci = (cc & 8) | ((cc & 7) ^ sw7);
            const bf16x8 bf = *(const bf16x8*)(brow + ci * 8);
            a0 = __builtin_amdgcn_mfma_f32_16x16x32_bf16(wa[0][ks], bf, a0, 0, 0, 0);
            a1 = __builtin_amdgcn_mfma_f32_16x16x32_bf16(wa[1][ks], bf, a1, 0, 0, 0);
            a2 = __builtin_amdgcn_mfma_f32_16x16x32_bf16(wa[2][ks], bf, a2, 0, 0, 0);
            a3 = __builtin_amdgcn_mfma_f32_16x16x32_bf16(wa[3][ks], bf, a3, 0, 0, 0);
        }

        unsigned short* hrow = hrow0 + el * 64;
        {
            f32x4 accs[4] = {a0, a1, a2, a3};
#pragma unroll
            for (int mt = 0; mt < 4; ++mt) {
                unsigned short pk[4];
#pragma unroll
                for (int r = 0; r < 4; ++r) pk[r] = f2bf(fmaxf(accs[mt][r], 0.f));
                const int hid   = mt * 16 + 4 * g;
                const int chunk = hid >> 3;
                const int off   = hid & 7;
                *(uint2*)(hrow + ((chunk ^ sw7) * 8 + off)) = *(uint2*)pk;
            }
        }

        const bf16x8 hb0 = *(const bf16x8*)(hrow + (((0 + g) ^ sw7) * 8));
        const bf16x8 hb1 = *(const bf16x8*)(hrow + (((4 + g) ^ sw7) * 8));
        f32x4 dn0 = {bias2s[0], bias2s[0], bias2s[0], bias2s[0]};
        f32x4 dn1 = {bias2s[1], bias2s[1], bias2s[1], bias2s[1]};
        dn0 = __builtin_amdgcn_mfma_f32_16x16x32_bf16(hb0, wb[0][0], dn0, 0, 0, 0);
        dn1 = __builtin_amdgcn_mfma_f32_16x16x32_bf16(hb0, wb[1][0], dn1, 0, 0, 0);
        dn0 = __builtin_amdgcn_mfma_f32_16x16x32_bf16(hb1, wb[0][1], dn0, 0, 0, 0);
        dn1 = __builtin_amdgcn_mfma_f32_16x16x32_bf16(hb1, wb[1][1], dn1, 0, 0, 0);

        if (nbase + 16 <= N) {
#pragma unroll
            for (int r = 0; r < 4; ++r) {
                float* dst = out + (size_t)(nbase + 4 * g + r) * 32 + el;
                dst[0]  = dn0[r];
                dst[16] = dn1[r];
            }
        } else {
#pragma unroll
            for (int r = 0; r < 4; ++r) {
                const int n = nbase + 4 * g + r;
                if (n < N) {
                    float* dst = out + (size_t)n * 32 + el;
                    dst[0]  = dn0[r];
                    dst[16] = dn1[r];
                }
            }
        }
    }
}

extern "C" void kernel_launch(void* const* d_in, const int* in_sizes, int n_in,
                              void* d_out, int out_size, void* d_ws, size_t ws_size,
                              hipStream_t stream) {
    const float* x     = (const float*)d_in[0];
    const int*   eidx  = (const int*)d_in[1];
    const float* eattr = (const float*)d_in[2];
    const float* u     = (const float*)d_in[3];
    const int*   batch = (const int*)d_in[4];
    const float* W1a   = (const float*)d_in[5];
    const float* b1a   = (const float*)d_in[6];
    const float* W1b   = (const float*)d_in[7];
    const float* b1b   = (const float*)d_in[8];
    const float* W2a   = (const float*)d_in[9];
    const float* b2a   = (const float*)d_in[10];
    const float* W2b   = (const float*)d_in[11];
    const float* b2b   = (const float*)d_in[12];
    float* out = (float*)d_out;

    const int N = in_sizes[0] / 32;
    const int E = in_sizes[1] / 2;
    const int* erow = eidx;
    const int* ecol = eidx + E;
    const int nb = (N + 255) / 256;

    // full-path ws: eattr_s E*64 | xbf N*64 | binned E*8 | sorted1 E*4
    //             | summed N*256 | counts N*4 | rowstart (N+1)*4 | cursor N*4
    //             | bucket_cursor 1KB | bsum 1KB
    const size_t need_full = (size_t)E * 64 + (size_t)N * 64 + (size_t)E * 8
                           + (size_t)E * 4 + (size_t)N * 256
                           + (size_t)(3 * N + 1) * 4 + 2048;

    if (ws_size >= need_full) {
        char* p = (char*)d_ws;
        unsigned short* eattr_s = (unsigned short*)p; p += (size_t)E * 64;
        unsigned short* xbf     = (unsigned short*)p; p += (size_t)N * 64;
        int2*  binned   = (int2*)p;  p += (size_t)E * 8;
        int*   sorted1  = (int*)p;   p += (size_t)E * 4;
        float* summed   = (float*)p; p += (size_t)N * 256;
        int*   counts   = (int*)p;   p += (size_t)N * 4;
        int*   rowstart = (int*)p;   p += (size_t)(N + 1) * 4;
        int*   cursor   = (int*)p;   p += (size_t)N * 4;
        int*   bucket_cursor = (int*)p; p += 1024;
        int*   bsum     = (int*)p;

        // zero summed + counts (contiguous)
        hipMemsetAsync(summed, 0, (size_t)N * 256 + (size_t)N * 4, stream);
        count_rows_convx<<<1024, 256, 0, stream>>>(erow, counts, E, x, xbf, N * 4);
        scan_blocks<<<nb, 256, 0, stream>>>(counts, rowstart, bsum, N);
        scan_bsum<<<1, 256, 0, stream>>>(bsum, nb);
        scan_add<<<nb, 256, 0, stream>>>(rowstart, cursor, bucket_cursor,
                                         bsum, N, E);
        bin_edges<<<1024, 256, 0, stream>>>(erow, ecol, bucket_cursor, binned, E);
        permute_gather_conv<<<512, 256, 0, stream>>>(binned, eattr, cursor,
                                                     sorted1, eattr_s, E);
        edge_mlp_v2<<<4096, 256, 0, stream>>>(xbf, sorted1, eattr_s,
                                              W1a, b1a, W1b, b1b, summed, E);
        node_mlp_mfma<<<784, 256, 0, stream>>>(x, summed, rowstart, u, batch,
                                               W2a, b2a, W2b, b2b, out, N);
    } else {
        // fallback: R14 layout/path (uses cursor as bucket_cursor dummy)
        int2*  sorted2  = (int2*)d_ws;
        float* summed   = (float*)(sorted2 + E);
        int*   counts   = (int*)(summed + (size_t)N * 64);
        int*   rowstart = counts + N;
        int*   cursor   = rowstart + (N + 1);
        int*   bucket_cursor = cursor + N;       // 256 ints
        int*   bsum     = bucket_cursor + 256;

        hipMemsetAsync(summed, 0, ((size_t)N * 64 + N) * sizeof(float), stream);
        count_rows_convx<<<1024, 256, 0, stream>>>(erow, counts, E, x, nullptr, 0);
        scan_blocks<<<nb, 256, 0, stream>>>(counts, rowstart, bsum, N);
        scan_bsum<<<1, 256, 0, stream>>>(bsum, nb);
        scan_add<<<nb, 256, 0, stream>>>(rowstart, cursor, bucket_cursor,
                                         bsum, N, E);
        permute_edges<<<1024, 256, 0, stream>>>(erow, ecol, cursor, sorted2, E);
        edge_mlp_mfma<<<4096, 256, 0, stream>>>(x, sorted2, eattr,
                                                W1a, b1a, W1b, b1b, summed, E);
        node_mlp_mfma<<<784, 256, 0, stream>>>(x, summed, rowstart, u, batch,
                                               W2a, b2a, W2b, b2b, out, N);
    }
}

// Round 19
// 298.568 us; speedup vs baseline: 4.0273x; 4.0273x over previous
//
#include <hip/hip_runtime.h>
#include <hip/hip_bf16.h>

// NodeModel: edge MLP ([x[col]||edge_attr] -> 64 relu -> 64 relu) -> scatter_mean
// over row -> node MLP ([x||agg||u[batch]] -> 64 relu -> 32).
// N=50000, E=1.6M, D_H=64.
//
// R19: R14 (best proven: 314.7us; edge kernel at the unique no-spill point)
// with the meta permute's 8x write amplification (12.8MB payload -> 101MB,
// ~117us) fixed by a two-pass partition that R18 attempted but killed with
// atomic contention (1.6M atomics on 196 counters -> 892us):
//  - bin_edges_v2: per 8192-edge block, LDS histogram of row>>8 (LDS atomics),
//    ONE global atomic per (block,bucket) (~38K total) to reserve ranges,
//    then ~330B contiguous meta runs -> near-full-line writes.
//  - place_edges: streams bucket-grouped metas; cursor[row] (50K counters,
//    contention-proven fine) gives exact positions; writes fall in a ~8MB
//    moving window -> L2 absorbs partial lines.
// Edge/node kernels = R14 verbatim.

typedef __attribute__((ext_vector_type(8))) short bf16x8;
typedef __attribute__((ext_vector_type(4))) float f32x4;

__device__ __forceinline__ unsigned short f2bf(float f) {
    __bf16 h = (__bf16)f;               // HW cvt (RNE)
    unsigned short u;
    __builtin_memcpy(&u, &h, 2);
    return u;
}

// ---------------- counting sort ----------------

__global__ __launch_bounds__(256) void count_rows(
    const int* __restrict__ erow, int* __restrict__ counts, int E)
{
    const int gid = blockIdx.x * blockDim.x + threadIdx.x;
    const int stride = gridDim.x * blockDim.x;
    const int n4 = E >> 2;
    for (int i = gid; i < n4; i += stride) {
        const int4 r = ((const int4*)erow)[i];
        atomicAdd(&counts[r.x], 1);
        atomicAdd(&counts[r.y], 1);
        atomicAdd(&counts[r.z], 1);
        atomicAdd(&counts[r.w], 1);
    }
    for (int i = (n4 << 2) + gid; i < E; i += stride)
        atomicAdd(&counts[erow[i]], 1);
}

__global__ __launch_bounds__(256) void scan_blocks(
    const int* __restrict__ counts, int* __restrict__ excl,
    int* __restrict__ bsum, int N)
{
    __shared__ int tmp[256];
    const int t = threadIdx.x;
    const int i = blockIdx.x * 256 + t;
    const int v = (i < N) ? counts[i] : 0;
    tmp[t] = v; __syncthreads();
#pragma unroll
    for (int o = 1; o < 256; o <<= 1) {
        const int a = (t >= o) ? tmp[t - o] : 0;
        __syncthreads();
        tmp[t] += a;
        __syncthreads();
    }
    if (i < N) excl[i] = tmp[t] - v;
    if (t == 255) bsum[blockIdx.x] = tmp[t];
}

__global__ __launch_bounds__(256) void scan_bsum(int* __restrict__ bsum, int nb)
{
    __shared__ int tmp[256];
    const int t = threadIdx.x;
    const int v = (t < nb) ? bsum[t] : 0;
    tmp[t] = v; __syncthreads();
#pragma unroll
    for (int o = 1; o < 256; o <<= 1) {
        const int a = (t >= o) ? tmp[t - o] : 0;
        __syncthreads();
        tmp[t] += a;
        __syncthreads();
    }
    if (t < nb) bsum[t] = tmp[t] - v;   // exclusive
}

__global__ __launch_bounds__(256) void scan_add(
    int* __restrict__ rowstart, int* __restrict__ cursor,
    int* __restrict__ bucket_cursor,
    const int* __restrict__ bsum, int N, int E)
{
    const int i = blockIdx.x * 256 + threadIdx.x;
    if (i < N) {
        const int v = rowstart[i] + bsum[blockIdx.x];
        rowstart[i] = v;
        cursor[i]   = v;
        if ((i & 255) == 0) bucket_cursor[i >> 8] = v;  // bucketstart: FREE
    }
    if (i == 0) rowstart[N] = E;
}

// ---- pass A: block-aggregated binning by row>>8. LDS histogram + ONE
// ---- global atomic per (block,bucket) (~38K total; R18's 1.6M-on-196
// ---- contention fixed). Metas land in ~330B contiguous runs. ----
#define BIN_CHUNK 8192
__global__ __launch_bounds__(256) void bin_edges_v2(
    const int* __restrict__ erow, const int* __restrict__ ecol,
    int* __restrict__ bucket_cursor, int2* __restrict__ binned, int E)
{
    __shared__ int hist[256];
    const int tid  = threadIdx.x;
    const int base = blockIdx.x * BIN_CHUNK;

    hist[tid] = 0;
    __syncthreads();
#pragma unroll 1
    for (int i = 0; i < BIN_CHUNK; i += 256) {
        const int e = base + i + tid;
        if (e < E) atomicAdd(&hist[erow[e] >> 8], 1);
    }
    __syncthreads();
    {
        const int cnt = hist[tid];
        int b = 0;
        if (cnt > 0) b = atomicAdd(&bucket_cursor[tid], cnt);
        __syncthreads();
        hist[tid] = b;                 // LDS now holds running global cursor
    }
    __syncthreads();
#pragma unroll 1
    for (int i = 0; i < BIN_CHUNK; i += 256) {
        const int e = base + i + tid;
        if (e < E) {
            const int r = erow[e];
            const int q = atomicAdd(&hist[r >> 8], 1);
            binned[q] = int2{e, (int)((unsigned)ecol[e] | ((unsigned)r << 16))};
        }
    }
}

// ---- pass B: bucket-grouped metas -> exact sorted position via cursor[row];
// ---- writes fall in a moving ~8MB window -> L2 absorbs partial lines. ----
__global__ __launch_bounds__(256) void place_edges(
    const int2* __restrict__ binned, int* __restrict__ cursor,
    int2* __restrict__ sorted2, int E)
{
    const int gid = blockIdx.x * blockDim.x + threadIdx.x;
    const int stride = gridDim.x * blockDim.x;
    for (int p = gid; p < E; p += stride) {
        const int2 m = binned[p];
        const int row = (int)((unsigned)m.y >> 16);   // LOGICAL shift
        const int pos = atomicAdd(&cursor[row], 1);
        sorted2[pos] = m;
    }
}

// ---- fallback: direct scatter (R14) ----
__global__ __launch_bounds__(256) void permute_edges(
    const int* __restrict__ erow, const int* __restrict__ ecol,
    int* __restrict__ cursor, int2* __restrict__ sorted2, int E)
{
    const int gid = blockIdx.x * blockDim.x + threadIdx.x;
    const int stride = gridDim.x * blockDim.x;
    for (int i = gid; i < E; i += stride) {
        const int r = erow[i];
        const int pos = atomicAdd(&cursor[r], 1);
        sorted2[pos] = int2{i, (int)((unsigned)ecol[i] | ((unsigned)r << 16))};
    }
}

// ---------------- edge MLP (R14 verbatim: register-resident, f32 gather) ----------------

__global__ __launch_bounds__(256, 3) void edge_mlp_mfma(
    const float* __restrict__ x,        // [N,32]
    const int2*  __restrict__ sorted2,  // [E] {eid, col|row<<16}
    const float* __restrict__ eattr,    // [E,32]
    const float* __restrict__ W1a,      // [64,64] (in,out)
    const float* __restrict__ b1a,      // [64]
    const float* __restrict__ W1b,      // [64,64]
    const float* __restrict__ b1b,      // [64]
    float* __restrict__ summed,         // [N,64]
    int E)
{
    __shared__ __align__(16) unsigned short H2[4 * 16 * 64];

    const int tid  = threadIdx.x;
    const int lane = tid & 63;
    const int wv   = tid >> 6;
    const int g    = lane >> 4;
    const int el   = lane & 15;

    unsigned short* const h2w = H2 + wv * (16 * 64);

    bf16x8 wa[4][2], wb[4][2];
    f32x4  bias1[4];
    float  bias2s[4];
#pragma unroll
    for (int mt = 0; mt < 4; ++mt) {
        const int o = mt * 16 + el;
#pragma unroll
        for (int ks = 0; ks < 2; ++ks) {
            bf16x8 ta, tb;
#pragma unroll
            for (int j = 0; j < 8; ++j) {
                const int k = ks * 32 + 8 * g + j;
                ta[j] = (short)f2bf(W1a[k * 64 + o]);
                tb[j] = (short)f2bf(W1b[k * 64 + o]);
            }
            wa[mt][ks] = ta;
            wb[mt][ks] = tb;
        }
#pragma unroll
        for (int r = 0; r < 4; ++r) bias1[mt][r] = b1a[mt * 16 + 4 * g + r];
        bias2s[mt] = b1b[o];
    }

    const int ntile = (E + 15) >> 4;
    const int wid   = blockIdx.x * 4 + wv;
    const int nw    = gridDim.x * 4;
    const int sw    = el & 7;

    for (int t = wid; t < ntile; t += nw) {
        const int ebase = t << 4;
        int2 s2; int row;
        if (ebase + el < E) {
            s2 = sorted2[ebase + el];
            row = (int)((unsigned)s2.y >> 16);
        } else { s2 = int2{0, 0}; row = -1; }

        bf16x8 bf0, bf1;
        {
            const float4* xp = (const float4*)(x + (size_t)(s2.y & 0xFFFF) * 32 + 8 * g);
            const float4* ap = (const float4*)(eattr + (size_t)s2.x * 32 + 8 * g);
            const float4 x0 = xp[0], x1 = xp[1];
            const float4 a0v = ap[0], a1v = ap[1];
            bf0[0] = (short)f2bf(x0.x); bf0[1] = (short)f2bf(x0.y);
            bf0[2] = (short)f2bf(x0.z); bf0[3] = (short)f2bf(x0.w);
            bf0[4] = (short)f2bf(x1.x); bf0[5] = (short)f2bf(x1.y);
            bf0[6] = (short)f2bf(x1.z); bf0[7] = (short)f2bf(x1.w);
            bf1[0] = (short)f2bf(a0v.x); bf1[1] = (short)f2bf(a0v.y);
            bf1[2] = (short)f2bf(a0v.z); bf1[3] = (short)f2bf(a0v.w);
            bf1[4] = (short)f2bf(a1v.x); bf1[5] = (short)f2bf(a1v.y);
            bf1[6] = (short)f2bf(a1v.z); bf1[7] = (short)f2bf(a1v.w);
        }

        f32x4 a0 = bias1[0], a1 = bias1[1], a2 = bias1[2], a3 = bias1[3];
        a0 = __builtin_amdgcn_mfma_f32_16x16x32_bf16(wa[0][0], bf0, a0, 0, 0, 0);
        a1 = __builtin_amdgcn_mfma_f32_16x16x32_bf16(wa[1][0], bf0, a1, 0, 0, 0);
        a2 = __builtin_amdgcn_mfma_f32_16x16x32_bf16(wa[2][0], bf0, a2, 0, 0, 0);
        a3 = __builtin_amdgcn_mfma_f32_16x16x32_bf16(wa[3][0], bf0, a3, 0, 0, 0);
        a0 = __builtin_amdgcn_mfma_f32_16x16x32_bf16(wa[0][1], bf1, a0, 0, 0, 0);
        a1 = __builtin_amdgcn_mfma_f32_16x16x32_bf16(wa[1][1], bf1, a1, 0, 0, 0);
        a2 = __builtin_amdgcn_mfma_f32_16x16x32_bf16(wa[2][1], bf1, a2, 0, 0, 0);
        a3 = __builtin_amdgcn_mfma_f32_16x16x32_bf16(wa[3][1], bf1, a3, 0, 0, 0);

        unsigned short* hrow = h2w + el * 64;
        {
            f32x4 accs[4] = {a0, a1, a2, a3};
#pragma unroll
            for (int mt = 0; mt < 4; ++mt) {
                unsigned short pk[4];
#pragma unroll
                for (int r = 0; r < 4; ++r) pk[r] = f2bf(fmaxf(accs[mt][r], 0.f));
                const int hid   = mt * 16 + 4 * g;
                const int chunk = hid >> 3;
                const int off   = hid & 7;
                *(uint2*)(hrow + ((chunk ^ sw) * 8 + off)) = *(uint2*)pk;
            }
        }

        const bf16x8 hb0 = *(const bf16x8*)(hrow + (((0 + g) ^ sw) * 8));
        const bf16x8 hb1 = *(const bf16x8*)(hrow + (((4 + g) ^ sw) * 8));
        f32x4 d0 = {bias2s[0], bias2s[0], bias2s[0], bias2s[0]};
        f32x4 d1 = {bias2s[1], bias2s[1], bias2s[1], bias2s[1]};
        f32x4 d2 = {bias2s[2], bias2s[2], bias2s[2], bias2s[2]};
        f32x4 d3 = {bias2s[3], bias2s[3], bias2s[3], bias2s[3]};
        d0 = __builtin_amdgcn_mfma_f32_16x16x32_bf16(hb0, wb[0][0], d0, 0, 0, 0);
        d1 = __builtin_amdgcn_mfma_f32_16x16x32_bf16(hb0, wb[1][0], d1, 0, 0, 0);
        d2 = __builtin_amdgcn_mfma_f32_16x16x32_bf16(hb0, wb[2][0], d2, 0, 0, 0);
        d3 = __builtin_amdgcn_mfma_f32_16x16x32_bf16(hb0, wb[3][0], d3, 0, 0, 0);
        d0 = __builtin_amdgcn_mfma_f32_16x16x32_bf16(hb1, wb[0][1], d0, 0, 0, 0);
        d1 = __builtin_amdgcn_mfma_f32_16x16x32_bf16(hb1, wb[1][1], d1, 0, 0, 0);
        d2 = __builtin_amdgcn_mfma_f32_16x16x32_bf16(hb1, wb[2][1], d2, 0, 0, 0);
        d3 = __builtin_amdgcn_mfma_f32_16x16x32_bf16(hb1, wb[3][1], d3, 0, 0, 0);

#pragma unroll
        for (int r = 0; r < 4; ++r) {
            d0[r] = fmaxf(d0[r], 0.f);
            d1[r] = fmaxf(d1[r], 0.f);
            d2[r] = fmaxf(d2[r], 0.f);
            d3[r] = fmaxf(d3[r], 0.f);
        }

        const int prevrow = __shfl(row, lane - 1);
        unsigned long long bmask =
            __ballot((g == 0) && (el > 0) && (row != prevrow));
        bmask = (bmask & 0xFFFEull) | 0x10000ull;

        int s = 0;
        while (s < 16) {
            const int e = s + 1 + (__ffsll(bmask >> (s + 1)) - 1);
            const int rowid = __shfl(row, s);
            if (rowid >= 0) {
                float s0 = 0.f, s1 = 0.f, s2v = 0.f, s3 = 0.f;
#pragma unroll
                for (int r = 0; r < 4; ++r) {
                    const int ej = 4 * g + r;
                    const bool in = (ej >= s) && (ej < e);
                    s0  += in ? d0[r] : 0.f;
                    s1  += in ? d1[r] : 0.f;
                    s2v += in ? d2[r] : 0.f;
                    s3  += in ? d3[r] : 0.f;
                }
                s0  += __shfl_xor(s0, 16);  s0  += __shfl_xor(s0, 32);
                s1  += __shfl_xor(s1, 16);  s1  += __shfl_xor(s1, 32);
                s2v += __shfl_xor(s2v, 16); s2v += __shfl_xor(s2v, 32);
                s3  += __shfl_xor(s3, 16);  s3  += __shfl_xor(s3, 32);
                const float val = (g == 0) ? s0 : (g == 1) ? s1
                                : (g == 2) ? s2v : s3;
                unsafeAtomicAdd(&summed[(size_t)rowid * 64 + lane], val);
            }
            s = e;
        }
    }
}

// ---------------- node MLP via MFMA (R14 verbatim) ----------------

__global__ __launch_bounds__(256, 2) void node_mlp_mfma(
    const float* __restrict__ x,        // [N,32]
    const float* __restrict__ summed,   // [N,64]
    const int*   __restrict__ rowstart, // [N+1]
    const float* __restrict__ u,        // [G,16]
    const int*   __restrict__ batch,    // [N]
    const float* __restrict__ W2a,      // [112,64]
    const float* __restrict__ b2a,      // [64]
    const float* __restrict__ W2b,      // [64,32]
    const float* __restrict__ b2b,      // [32]
    float* __restrict__ out,            // [N,32]
    int N)
{
    __shared__ __align__(16) unsigned short In[64 * 128];  // 16KB
    __shared__ __align__(16) unsigned short H[64 * 64];    // 8KB

    const int tid  = threadIdx.x;
    const int lane = tid & 63;
    const int wv   = tid >> 6;
    const int g    = lane >> 4;
    const int el   = lane & 15;

    bf16x8 wa[4][4];
    f32x4  bias1[4];
#pragma unroll
    for (int mt = 0; mt < 4; ++mt) {
        const int o = mt * 16 + el;
#pragma unroll
        for (int ks = 0; ks < 4; ++ks) {
            bf16x8 ta;
#pragma unroll
            for (int j = 0; j < 8; ++j) {
                const int k = ks * 32 + 8 * g + j;
                ta[j] = (k < 112) ? (short)f2bf(W2a[k * 64 + o]) : (short)0;
            }
            wa[mt][ks] = ta;
        }
#pragma unroll
        for (int r = 0; r < 4; ++r) bias1[mt][r] = b2a[mt * 16 + 4 * g + r];
    }
    bf16x8 wb[2][2];
    float  bias2s[2];
#pragma unroll
    for (int nt = 0; nt < 2; ++nt) {
        const int o = nt * 16 + el;
#pragma unroll
        for (int ks = 0; ks < 2; ++ks) {
            bf16x8 tb;
#pragma unroll
            for (int j = 0; j < 8; ++j) {
                const int k = ks * 32 + 8 * g + j;
                tb[j] = (short)f2bf(W2b[k * 32 + o]);
            }
            wb[nt][ks] = tb;
        }
        bias2s[nt] = b2b[o];
    }

    unsigned short* const inrow = In + (wv * 16) * 128;
    unsigned short* const hrow0 = H + (wv * 16) * 64;

    const int ntile = (N + 15) >> 4;
    const int wid   = blockIdx.x * 4 + wv;
    const int nw    = gridDim.x * 4;

    for (int t = wid; t < ntile; t += nw) {
        const int nbase = t << 4;
        {
            const int le = lane >> 2;
            const int p  = lane & 3;
            const int n  = nbase + le;
            float4 v[8];
            if (n < N) {
                if (p == 0) {
                    const float4* xp = (const float4*)(x + (size_t)n * 32);
#pragma unroll
                    for (int q = 0; q < 8; ++q) v[q] = xp[q];
                } else if (p < 3) {
                    const int cnt = rowstart[n + 1] - rowstart[n];
                    const float inv = 1.0f / fmaxf((float)cnt, 1.0f);
                    const float4* sp = (const float4*)(summed + (size_t)n * 64 + (p - 1) * 32);
#pragma unroll
                    for (int q = 0; q < 8; ++q) {
                        v[q] = sp[q];
                        v[q].x *= inv; v[q].y *= inv; v[q].z *= inv; v[q].w *= inv;
                    }
                } else {
                    const int gb = batch[n];
                    const float4* up = (const float4*)(u + (size_t)gb * 16);
#pragma unroll
                    for (int q = 0; q < 4; ++q) v[q] = up[q];
#pragma unroll
                    for (int q = 4; q < 8; ++q) v[q] = float4{0.f, 0.f, 0.f, 0.f};
                }
            } else {
#pragma unroll
                for (int q = 0; q < 8; ++q) v[q] = float4{0.f, 0.f, 0.f, 0.f};
            }
            const int sw = le & 7;
            unsigned short* row = inrow + le * 128;
#pragma unroll
            for (int q = 0; q < 4; ++q) {
                bf16x8 c;
                const float4 va = v[2 * q], vb = v[2 * q + 1];
                c[0] = (short)f2bf(va.x); c[1] = (short)f2bf(va.y);
                c[2] = (short)f2bf(va.z); c[3] = (short)f2bf(va.w);
                c[4] = (short)f2bf(vb.x); c[5] = (short)f2bf(vb.y);
                c[6] = (short)f2bf(vb.z); c[7] = (short)f2bf(vb.w);
                const int cc = 4 * p + q;
                const int ci = (cc & 8) | ((cc & 7) ^ sw);
                *(bf16x8*)(row + ci * 8) = c;
            }
        }

        const unsigned short* brow = inrow + el * 128;
        const int sw7 = el & 7;
        f32x4 a0 = bias1[0], a1 = bias1[1], a2 = bias1[2], a3 = bias1[3];
#pragma unroll
        for (int ks = 0; ks < 4; ++ks) {
            const int cc = ks * 4 + g;
            const int ci = (cc & 8) | ((cc & 7) ^ sw7);
            const bf16x8 bf = *(const bf16x8*)(brow + ci * 8);
            a0 = __builtin_amdgcn_mfma_f32_16x16x32_bf16(wa[0][ks], bf, a0, 0, 0, 0);
            a1 = __builtin_amdgcn_mfma_f32_16x16x32_bf16(wa[1][ks], bf, a1, 0, 0, 0);
            a2 = __builtin_amdgcn_mfma_f32_16x16x32_bf16(wa[2][ks], bf, a2, 0, 0, 0);
            a3 = __builtin_amdgcn_mfma_f32_16x16x32_bf16(wa[3][ks], bf, a3, 0, 0, 0);
        }

        unsigned short* hrow = hrow0 + el * 64;
        {
            f32x4 accs[4] = {a0, a1, a2, a3};
#pragma unroll
            for (int mt = 0; mt < 4; ++mt) {
                unsigned short pk[4];
#pragma unroll
                for (int r = 0; r < 4; ++r) pk[r] = f2bf(fmaxf(accs[mt][r], 0.f));
                const int hid   = mt * 16 + 4 * g;
                const int chunk = hid >> 3;
                const int off   = hid & 7;
                *(uint2*)(hrow + ((chunk ^ sw7) * 8 + off)) = *(uint2*)pk;
            }
        }

        const bf16x8 hb0 = *(const bf16x8*)(hrow + (((0 + g) ^ sw7) * 8));
        const bf16x8 hb1 = *(const bf16x8*)(hrow + (((4 + g) ^ sw7) * 8));
        f32x4 dn0 = {bias2s[0], bias2s[0], bias2s[0], bias2s[0]};
        f32x4 dn1 = {bias2s[1], bias2s[1], bias2s[1], bias2s[1]};
        dn0 = __builtin_amdgcn_mfma_f32_16x16x32_bf16(hb0, wb[0][0], dn0, 0, 0, 0);
        dn1 = __builtin_amdgcn_mfma_f32_16x16x32_bf16(hb0, wb[1][0], dn1, 0, 0, 0);
        dn0 = __builtin_amdgcn_mfma_f32_16x16x32_bf16(hb1, wb[0][1], dn0, 0, 0, 0);
        dn1 = __builtin_amdgcn_mfma_f32_16x16x32_bf16(hb1, wb[1][1], dn1, 0, 0, 0);

        if (nbase + 16 <= N) {
#pragma unroll
            for (int r = 0; r < 4; ++r) {
                float* dst = out + (size_t)(nbase + 4 * g + r) * 32 + el;
                dst[0]  = dn0[r];
                dst[16] = dn1[r];
            }
        } else {
#pragma unroll
            for (int r = 0; r < 4; ++r) {
                const int n = nbase + 4 * g + r;
                if (n < N) {
                    float* dst = out + (size_t)n * 32 + el;
                    dst[0]  = dn0[r];
                    dst[16] = dn1[r];
                }
            }
        }
    }
}

extern "C" void kernel_launch(void* const* d_in, const int* in_sizes, int n_in,
                              void* d_out, int out_size, void* d_ws, size_t ws_size,
                              hipStream_t stream) {
    const float* x     = (const float*)d_in[0];
    const int*   eidx  = (const int*)d_in[1];
    const float* eattr = (const float*)d_in[2];
    const float* u     = (const float*)d_in[3];
    const int*   batch = (const int*)d_in[4];
    const float* W1a   = (const float*)d_in[5];
    const float* b1a   = (const float*)d_in[6];
    const float* W1b   = (const float*)d_in[7];
    const float* b1b   = (const float*)d_in[8];
    const float* W2a   = (const float*)d_in[9];
    const float* b2a   = (const float*)d_in[10];
    const float* W2b   = (const float*)d_in[11];
    const float* b2b   = (const float*)d_in[12];
    float* out = (float*)d_out;

    const int N = in_sizes[0] / 32;
    const int E = in_sizes[1] / 2;
    const int* erow = eidx;
    const int* ecol = eidx + E;
    const int nb = (N + 255) / 256;

    // ws: sorted2 E*8 | binned E*8 | summed N*256 | counts N*4
    //   | rowstart (N+1)*4 | cursor N*4 | bucket_cursor 1KB | bsum 1KB
    const size_t need_full = (size_t)E * 16 + (size_t)N * 256
                           + (size_t)(3 * N + 1) * 4 + 2048;

    if (ws_size >= need_full) {
        char* p = (char*)d_ws;
        int2*  sorted2  = (int2*)p;  p += (size_t)E * 8;
        int2*  binned   = (int2*)p;  p += (size_t)E * 8;
        float* summed   = (float*)p; p += (size_t)N * 256;
        int*   counts   = (int*)p;   p += (size_t)N * 4;
        int*   rowstart = (int*)p;   p += (size_t)(N + 1) * 4;
        int*   cursor   = (int*)p;   p += (size_t)N * 4;
        int*   bucket_cursor = (int*)p; p += 1024;
        int*   bsum     = (int*)p;

        hipMemsetAsync(summed, 0, (size_t)N * 256 + (size_t)N * 4, stream);
        count_rows<<<1024, 256, 0, stream>>>(erow, counts, E);
        scan_blocks<<<nb, 256, 0, stream>>>(counts, rowstart, bsum, N);
        scan_bsum<<<1, 256, 0, stream>>>(bsum, nb);
        scan_add<<<nb, 256, 0, stream>>>(rowstart, cursor, bucket_cursor,
                                         bsum, N, E);
        const int nbin = (E + BIN_CHUNK - 1) / BIN_CHUNK;
        bin_edges_v2<<<nbin, 256, 0, stream>>>(erow, ecol, bucket_cursor,
                                               binned, E);
        place_edges<<<512, 256, 0, stream>>>(binned, cursor, sorted2, E);
        edge_mlp_mfma<<<4096, 256, 0, stream>>>(x, sorted2, eattr,
                                                W1a, b1a, W1b, b1b, summed, E);
        node_mlp_mfma<<<784, 256, 0, stream>>>(x, summed, rowstart, u, batch,
                                               W2a, b2a, W2b, b2b, out, N);
    } else {
        // fallback: R14 exact
        int2*  sorted2  = (int2*)d_ws;
        float* summed   = (float*)(sorted2 + E);
        int*   counts   = (int*)(summed + (size_t)N * 64);
        int*   rowstart = counts + N;
        int*   cursor   = rowstart + (N + 1);
        int*   bucket_cursor = cursor + N;       // 256 ints
        int*   bsum     = bucket_cursor + 256;

        hipMemsetAsync(summed, 0, ((size_t)N * 64 + N) * sizeof(float), stream);
        count_rows<<<1024, 256, 0, stream>>>(erow, counts, E);
        scan_blocks<<<nb, 256, 0, stream>>>(counts, rowstart, bsum, N);
        scan_bsum<<<1, 256, 0, stream>>>(bsum, nb);
        scan_add<<<nb, 256, 0, stream>>>(rowstart, cursor, bucket_cursor,
                                         bsum, N, E);
        permute_edges<<<1024, 256, 0, stream>>>(erow, ecol, cursor, sorted2, E);
        edge_mlp_mfma<<<4096, 256, 0, stream>>>(x, sorted2, eattr,
                                                W1a, b1a, W1b, b1b, summed, E);
        node_mlp_mfma<<<784, 256, 0, stream>>>(x, summed, rowstart, u, batch,
                                               W2a, b2a, W2b, b2b, out, N);
    }
}

// Round 20
// 294.611 us; speedup vs baseline: 4.0814x; 1.0134x over previous
//
#include <hip/hip_runtime.h>
#include <hip/hip_bf16.h>

// NodeModel: edge MLP ([x[col]||edge_attr] -> 64 relu -> 64 relu) -> scatter_mean
// over row -> node MLP ([x||agg||u[batch]] -> 64 relu -> 32).
// N=50000, E=1.6M, D_H=64.
//
// R20: R19 (298.6us best: two-pass low-amp partition + R14 edge/node kernels)
// + bf16 x-table for the edge kernel (R16/R17-proven pieces):
//  - count_rows_convx converts x (6.4MB f32) -> xbf (3.2MB bf16) once.
//    3.2MB FITS a 4MB per-XCD L2 -> x gathers become near-always L2 hits.
//  - edge kernel loads bf0 DIRECTLY from xbf (16 fewer cvt/lane/tile).
// eattr stays f32 random-gather (streamed alternatives are net-negative:
// R16/R17 quantified +60-105us preprocessing for -40us edge).

typedef __attribute__((ext_vector_type(8))) short bf16x8;
typedef __attribute__((ext_vector_type(4))) float f32x4;

__device__ __forceinline__ unsigned short f2bf(float f) {
    __bf16 h = (__bf16)f;               // HW cvt (RNE)
    unsigned short u;
    __builtin_memcpy(&u, &h, 2);
    return u;
}
__device__ __forceinline__ bf16x8 pack8(const float4 a, const float4 b) {
    bf16x8 c;
    c[0] = (short)f2bf(a.x); c[1] = (short)f2bf(a.y);
    c[2] = (short)f2bf(a.z); c[3] = (short)f2bf(a.w);
    c[4] = (short)f2bf(b.x); c[5] = (short)f2bf(b.y);
    c[6] = (short)f2bf(b.z); c[7] = (short)f2bf(b.w);
    return c;
}

// ---------------- counting sort (+ x -> bf16 convert) ----------------

__global__ __launch_bounds__(256) void count_rows_convx(
    const int* __restrict__ erow, int* __restrict__ counts, int E,
    const float* __restrict__ x, unsigned short* __restrict__ xbf, int nx8)
{
    const int gid = blockIdx.x * blockDim.x + threadIdx.x;
    const int stride = gridDim.x * blockDim.x;
    for (int i = gid; i < nx8; i += stride) {
        const float4 a = ((const float4*)x)[2 * i];
        const float4 b = ((const float4*)x)[2 * i + 1];
        *(bf16x8*)(xbf + (size_t)i * 8) = pack8(a, b);
    }
    const int n4 = E >> 2;
    for (int i = gid; i < n4; i += stride) {
        const int4 r = ((const int4*)erow)[i];
        atomicAdd(&counts[r.x], 1);
        atomicAdd(&counts[r.y], 1);
        atomicAdd(&counts[r.z], 1);
        atomicAdd(&counts[r.w], 1);
    }
    for (int i = (n4 << 2) + gid; i < E; i += stride)
        atomicAdd(&counts[erow[i]], 1);
}

__global__ __launch_bounds__(256) void scan_blocks(
    const int* __restrict__ counts, int* __restrict__ excl,
    int* __restrict__ bsum, int N)
{
    __shared__ int tmp[256];
    const int t = threadIdx.x;
    const int i = blockIdx.x * 256 + t;
    const int v = (i < N) ? counts[i] : 0;
    tmp[t] = v; __syncthreads();
#pragma unroll
    for (int o = 1; o < 256; o <<= 1) {
        const int a = (t >= o) ? tmp[t - o] : 0;
        __syncthreads();
        tmp[t] += a;
        __syncthreads();
    }
    if (i < N) excl[i] = tmp[t] - v;
    if (t == 255) bsum[blockIdx.x] = tmp[t];
}

__global__ __launch_bounds__(256) void scan_bsum(int* __restrict__ bsum, int nb)
{
    __shared__ int tmp[256];
    const int t = threadIdx.x;
    const int v = (t < nb) ? bsum[t] : 0;
    tmp[t] = v; __syncthreads();
#pragma unroll
    for (int o = 1; o < 256; o <<= 1) {
        const int a = (t >= o) ? tmp[t - o] : 0;
        __syncthreads();
        tmp[t] += a;
        __syncthreads();
    }
    if (t < nb) bsum[t] = tmp[t] - v;   // exclusive
}

__global__ __launch_bounds__(256) void scan_add(
    int* __restrict__ rowstart, int* __restrict__ cursor,
    int* __restrict__ bucket_cursor,
    const int* __restrict__ bsum, int N, int E)
{
    const int i = blockIdx.x * 256 + threadIdx.x;
    if (i < N) {
        const int v = rowstart[i] + bsum[blockIdx.x];
        rowstart[i] = v;
        cursor[i]   = v;
        if ((i & 255) == 0) bucket_cursor[i >> 8] = v;  // bucketstart: FREE
    }
    if (i == 0) rowstart[N] = E;
}

// ---- pass A: block-aggregated binning by row>>8 (R19-proven) ----
#define BIN_CHUNK 8192
__global__ __launch_bounds__(256) void bin_edges_v2(
    const int* __restrict__ erow, const int* __restrict__ ecol,
    int* __restrict__ bucket_cursor, int2* __restrict__ binned, int E)
{
    __shared__ int hist[256];
    const int tid  = threadIdx.x;
    const int base = blockIdx.x * BIN_CHUNK;

    hist[tid] = 0;
    __syncthreads();
#pragma unroll 1
    for (int i = 0; i < BIN_CHUNK; i += 256) {
        const int e = base + i + tid;
        if (e < E) atomicAdd(&hist[erow[e] >> 8], 1);
    }
    __syncthreads();
    {
        const int cnt = hist[tid];
        int b = 0;
        if (cnt > 0) b = atomicAdd(&bucket_cursor[tid], cnt);
        __syncthreads();
        hist[tid] = b;                 // LDS now holds running global cursor
    }
    __syncthreads();
#pragma unroll 1
    for (int i = 0; i < BIN_CHUNK; i += 256) {
        const int e = base + i + tid;
        if (e < E) {
            const int r = erow[e];
            const int q = atomicAdd(&hist[r >> 8], 1);
            binned[q] = int2{e, (int)((unsigned)ecol[e] | ((unsigned)r << 16))};
        }
    }
}

// ---- pass B: bucket-grouped metas -> exact position (R19-proven) ----
__global__ __launch_bounds__(256) void place_edges(
    const int2* __restrict__ binned, int* __restrict__ cursor,
    int2* __restrict__ sorted2, int E)
{
    const int gid = blockIdx.x * blockDim.x + threadIdx.x;
    const int stride = gridDim.x * blockDim.x;
    for (int p = gid; p < E; p += stride) {
        const int2 m = binned[p];
        const int row = (int)((unsigned)m.y >> 16);   // LOGICAL shift
        const int pos = atomicAdd(&cursor[row], 1);
        sorted2[pos] = m;
    }
}

// ---- fallback: direct scatter (R14) ----
__global__ __launch_bounds__(256) void permute_edges(
    const int* __restrict__ erow, const int* __restrict__ ecol,
    int* __restrict__ cursor, int2* __restrict__ sorted2, int E)
{
    const int gid = blockIdx.x * blockDim.x + threadIdx.x;
    const int stride = gridDim.x * blockDim.x;
    for (int i = gid; i < E; i += stride) {
        const int r = erow[i];
        const int pos = atomicAdd(&cursor[r], 1);
        sorted2[pos] = int2{i, (int)((unsigned)ecol[i] | ((unsigned)r << 16))};
    }
}

// ---------------- edge MLP (R14 structure + bf16 x-table) ----------------

__global__ __launch_bounds__(256, 3) void edge_mlp_mfma(
    const unsigned short* __restrict__ xbf,  // [N,32] bf16 (3.2MB, L2-resident)
    const int2*  __restrict__ sorted2,       // [E] {eid, col|row<<16}
    const float* __restrict__ eattr,         // [E,32] f32
    const float* __restrict__ W1a,  const float* __restrict__ b1a,
    const float* __restrict__ W1b,  const float* __restrict__ b1b,
    float* __restrict__ summed, int E)
{
    __shared__ __align__(16) unsigned short H2[4 * 16 * 64];

    const int tid  = threadIdx.x;
    const int lane = tid & 63;
    const int wv   = tid >> 6;
    const int g    = lane >> 4;
    const int el   = lane & 15;

    unsigned short* const h2w = H2 + wv * (16 * 64);

    bf16x8 wa[4][2], wb[4][2];
    f32x4  bias1[4];
    float  bias2s[4];
#pragma unroll
    for (int mt = 0; mt < 4; ++mt) {
        const int o = mt * 16 + el;
#pragma unroll
        for (int ks = 0; ks < 2; ++ks) {
            bf16x8 ta, tb;
#pragma unroll
            for (int j = 0; j < 8; ++j) {
                const int k = ks * 32 + 8 * g + j;
                ta[j] = (short)f2bf(W1a[k * 64 + o]);
                tb[j] = (short)f2bf(W1b[k * 64 + o]);
            }
            wa[mt][ks] = ta;
            wb[mt][ks] = tb;
        }
#pragma unroll
        for (int r = 0; r < 4; ++r) bias1[mt][r] = b1a[mt * 16 + 4 * g + r];
        bias2s[mt] = b1b[o];
    }

    const int ntile = (E + 15) >> 4;
    const int wid   = blockIdx.x * 4 + wv;
    const int nw    = gridDim.x * 4;
    const int sw    = el & 7;

    for (int t = wid; t < ntile; t += nw) {
        const int ebase = t << 4;
        int2 s2; int row;
        if (ebase + el < E) {
            s2 = sorted2[ebase + el];
            row = (int)((unsigned)s2.y >> 16);
        } else { s2 = int2{0, 0}; row = -1; }

        // x fragment: direct bf16 load (L2-resident table, zero cvt)
        const bf16x8 bf0 = *(const bf16x8*)(xbf + (size_t)(s2.y & 0xFFFF) * 32 + 8 * g);
        // eattr fragment: f32 random gather + cvt (unavoidable: 204MB once)
        bf16x8 bf1;
        {
            const float4* ap = (const float4*)(eattr + (size_t)s2.x * 32 + 8 * g);
            bf1 = pack8(ap[0], ap[1]);
        }

        f32x4 a0 = bias1[0], a1 = bias1[1], a2 = bias1[2], a3 = bias1[3];
        a0 = __builtin_amdgcn_mfma_f32_16x16x32_bf16(wa[0][0], bf0, a0, 0, 0, 0);
        a1 = __builtin_amdgcn_mfma_f32_16x16x32_bf16(wa[1][0], bf0, a1, 0, 0, 0);
        a2 = __builtin_amdgcn_mfma_f32_16x16x32_bf16(wa[2][0], bf0, a2, 0, 0, 0);
        a3 = __builtin_amdgcn_mfma_f32_16x16x32_bf16(wa[3][0], bf0, a3, 0, 0, 0);
        a0 = __builtin_amdgcn_mfma_f32_16x16x32_bf16(wa[0][1], bf1, a0, 0, 0, 0);
        a1 = __builtin_amdgcn_mfma_f32_16x16x32_bf16(wa[1][1], bf1, a1, 0, 0, 0);
        a2 = __builtin_amdgcn_mfma_f32_16x16x32_bf16(wa[2][1], bf1, a2, 0, 0, 0);
        a3 = __builtin_amdgcn_mfma_f32_16x16x32_bf16(wa[3][1], bf1, a3, 0, 0, 0);

        unsigned short* hrow = h2w + el * 64;
        {
            f32x4 accs[4] = {a0, a1, a2, a3};
#pragma unroll
            for (int mt = 0; mt < 4; ++mt) {
                unsigned short pk[4];
#pragma unroll
                for (int r = 0; r < 4; ++r) pk[r] = f2bf(fmaxf(accs[mt][r], 0.f));
                const int hid   = mt * 16 + 4 * g;
                const int chunk = hid >> 3;
                const int off   = hid & 7;
                *(uint2*)(hrow + ((chunk ^ sw) * 8 + off)) = *(uint2*)pk;
            }
        }

        const bf16x8 hb0 = *(const bf16x8*)(hrow + (((0 + g) ^ sw) * 8));
        const bf16x8 hb1 = *(const bf16x8*)(hrow + (((4 + g) ^ sw) * 8));
        f32x4 d0 = {bias2s[0], bias2s[0], bias2s[0], bias2s[0]};
        f32x4 d1 = {bias2s[1], bias2s[1], bias2s[1], bias2s[1]};
        f32x4 d2 = {bias2s[2], bias2s[2], bias2s[2], bias2s[2]};
        f32x4 d3 = {bias2s[3], bias2s[3], bias2s[3], bias2s[3]};
        d0 = __builtin_amdgcn_mfma_f32_16x16x32_bf16(hb0, wb[0][0], d0, 0, 0, 0);
        d1 = __builtin_amdgcn_mfma_f32_16x16x32_bf16(hb0, wb[1][0], d1, 0, 0, 0);
        d2 = __builtin_amdgcn_mfma_f32_16x16x32_bf16(hb0, wb[2][0], d2, 0, 0, 0);
        d3 = __builtin_amdgcn_mfma_f32_16x16x32_bf16(hb0, wb[3][0], d3, 0, 0, 0);
        d0 = __builtin_amdgcn_mfma_f32_16x16x32_bf16(hb1, wb[0][1], d0, 0, 0, 0);
        d1 = __builtin_amdgcn_mfma_f32_16x16x32_bf16(hb1, wb[1][1], d1, 0, 0, 0);
        d2 = __builtin_amdgcn_mfma_f32_16x16x32_bf16(hb1, wb[2][1], d2, 0, 0, 0);
        d3 = __builtin_amdgcn_mfma_f32_16x16x32_bf16(hb1, wb[3][1], d3, 0, 0, 0);

#pragma unroll
        for (int r = 0; r < 4; ++r) {
            d0[r] = fmaxf(d0[r], 0.f);
            d1[r] = fmaxf(d1[r], 0.f);
            d2[r] = fmaxf(d2[r], 0.f);
            d3[r] = fmaxf(d3[r], 0.f);
        }

        const int prevrow = __shfl(row, lane - 1);
        unsigned long long bmask =
            __ballot((g == 0) && (el > 0) && (row != prevrow));
        bmask = (bmask & 0xFFFEull) | 0x10000ull;

        int s = 0;
        while (s < 16) {
            const int e = s + 1 + (__ffsll(bmask >> (s + 1)) - 1);
            const int rowid = __shfl(row, s);
            if (rowid >= 0) {
                float s0 = 0.f, s1 = 0.f, s2v = 0.f, s3 = 0.f;
#pragma unroll
                for (int r = 0; r < 4; ++r) {
                    const int ej = 4 * g + r;
                    const bool in = (ej >= s) && (ej < e);
                    s0  += in ? d0[r] : 0.f;
                    s1  += in ? d1[r] : 0.f;
                    s2v += in ? d2[r] : 0.f;
                    s3  += in ? d3[r] : 0.f;
                }
                s0  += __shfl_xor(s0, 16);  s0  += __shfl_xor(s0, 32);
                s1  += __shfl_xor(s1, 16);  s1  += __shfl_xor(s1, 32);
                s2v += __shfl_xor(s2v, 16); s2v += __shfl_xor(s2v, 32);
                s3  += __shfl_xor(s3, 16);  s3  += __shfl_xor(s3, 32);
                const float val = (g == 0) ? s0 : (g == 1) ? s1
                                : (g == 2) ? s2v : s3;
                unsafeAtomicAdd(&summed[(size_t)rowid * 64 + lane], val);
            }
            s = e;
        }
    }
}

// ---------------- node MLP via MFMA (R14 verbatim) ----------------

__global__ __launch_bounds__(256, 2) void node_mlp_mfma(
    const float* __restrict__ x,        // [N,32]
    const float* __restrict__ summed,   // [N,64]
    const int*   __restrict__ rowstart, // [N+1]
    const float* __restrict__ u,        // [G,16]
    const int*   __restrict__ batch,    // [N]
    const float* __restrict__ W2a,      // [112,64]
    const float* __restrict__ b2a,      // [64]
    const float* __restrict__ W2b,      // [64,32]
    const float* __restrict__ b2b,      // [32]
    float* __restrict__ out,            // [N,32]
    int N)
{
    __shared__ __align__(16) unsigned short In[64 * 128];  // 16KB
    __shared__ __align__(16) unsigned short H[64 * 64];    // 8KB

    const int tid  = threadIdx.x;
    const int lane = tid & 63;
    const int wv   = tid >> 6;
    const int g    = lane >> 4;
    const int el   = lane & 15;

    bf16x8 wa[4][4];
    f32x4  bias1[4];
#pragma unroll
    for (int mt = 0; mt < 4; ++mt) {
        const int o = mt * 16 + el;
#pragma unroll
        for (int ks = 0; ks < 4; ++ks) {
            bf16x8 ta;
#pragma unroll
            for (int j = 0; j < 8; ++j) {
                const int k = ks * 32 + 8 * g + j;
                ta[j] = (k < 112) ? (short)f2bf(W2a[k * 64 + o]) : (short)0;
            }
            wa[mt][ks] = ta;
        }
#pragma unroll
        for (int r = 0; r < 4; ++r) bias1[mt][r] = b2a[mt * 16 + 4 * g + r];
    }
    bf16x8 wb[2][2];
    float  bias2s[2];
#pragma unroll
    for (int nt = 0; nt < 2; ++nt) {
        const int o = nt * 16 + el;
#pragma unroll
        for (int ks = 0; ks < 2; ++ks) {
            bf16x8 tb;
#pragma unroll
            for (int j = 0; j < 8; ++j) {
                const int k = ks * 32 + 8 * g + j;
                tb[j] = (short)f2bf(W2b[k * 32 + o]);
            }
            wb[nt][ks] = tb;
        }
        bias2s[nt] = b2b[o];
    }

    unsigned short* const inrow = In + (wv * 16) * 128;
    unsigned short* const hrow0 = H + (wv * 16) * 64;

    const int ntile = (N + 15) >> 4;
    const int wid   = blockIdx.x * 4 + wv;
    const int nw    = gridDim.x * 4;

    for (int t = wid; t < ntile; t += nw) {
        const int nbase = t << 4;
        {
            const int le = lane >> 2;
            const int p  = lane & 3;
            const int n  = nbase + le;
            float4 v[8];
            if (n < N) {
                if (p == 0) {
                    const float4* xp = (const float4*)(x + (size_t)n * 32);
#pragma unroll
                    for (int q = 0; q < 8; ++q) v[q] = xp[q];
                } else if (p < 3) {
                    const int cnt = rowstart[n + 1] - rowstart[n];
                    const float inv = 1.0f / fmaxf((float)cnt, 1.0f);
                    const float4* sp = (const float4*)(summed + (size_t)n * 64 + (p - 1) * 32);
#pragma unroll
                    for (int q = 0; q < 8; ++q) {
                        v[q] = sp[q];
                        v[q].x *= inv; v[q].y *= inv; v[q].z *= inv; v[q].w *= inv;
                    }
                } else {
                    const int gb = batch[n];
                    const float4* up = (const float4*)(u + (size_t)gb * 16);
#pragma unroll
                    for (int q = 0; q < 4; ++q) v[q] = up[q];
#pragma unroll
                    for (int q = 4; q < 8; ++q) v[q] = float4{0.f, 0.f, 0.f, 0.f};
                }
            } else {
#pragma unroll
                for (int q = 0; q < 8; ++q) v[q] = float4{0.f, 0.f, 0.f, 0.f};
            }
            const int sw = le & 7;
            unsigned short* row = inrow + le * 128;
#pragma unroll
            for (int q = 0; q < 4; ++q) {
                const int cc = 4 * p + q;
                const int ci = (cc & 8) | ((cc & 7) ^ sw);
                *(bf16x8*)(row + ci * 8) = pack8(v[2 * q], v[2 * q + 1]);
            }
        }

        const unsigned short* brow = inrow + el * 128;
        const int sw7 = el & 7;
        f32x4 a0 = bias1[0], a1 = bias1[1], a2 = bias1[2], a3 = bias1[3];
#pragma unroll
        for (int ks = 0; ks < 4; ++ks) {
            const int cc = ks * 4 + g;
            const int ci = (cc & 8) | ((cc & 7) ^ sw7);
            const bf16x8 bf = *(const bf16x8*)(brow + ci * 8);
            a0 = __builtin_amdgcn_mfma_f32_16x16x32_bf16(wa[0][ks], bf, a0, 0, 0, 0);
            a1 = __builtin_amdgcn_mfma_f32_16x16x32_bf16(wa[1][ks], bf, a1, 0, 0, 0);
            a2 = __builtin_amdgcn_mfma_f32_16x16x32_bf16(wa[2][ks], bf, a2, 0, 0, 0);
            a3 = __builtin_amdgcn_mfma_f32_16x16x32_bf16(wa[3][ks], bf, a3, 0, 0, 0);
        }

        unsigned short* hrow = hrow0 + el * 64;
        {
            f32x4 accs[4] = {a0, a1, a2, a3};
#pragma unroll
            for (int mt = 0; mt < 4; ++mt) {
                unsigned short pk[4];
#pragma unroll
                for (int r = 0; r < 4; ++r) pk[r] = f2bf(fmaxf(accs[mt][r], 0.f));
                const int hid   = mt * 16 + 4 * g;
                const int chunk = hid >> 3;
                const int off   = hid & 7;
                *(uint2*)(hrow + ((chunk ^ sw7) * 8 + off)) = *(uint2*)pk;
            }
        }

        const bf16x8 hb0 = *(const bf16x8*)(hrow + (((0 + g) ^ sw7) * 8));
        const bf16x8 hb1 = *(const bf16x8*)(hrow + (((4 + g) ^ sw7) * 8));
        f32x4 dn0 = {bias2s[0], bias2s[0], bias2s[0], bias2s[0]};
        f32x4 dn1 = {bias2s[1], bias2s[1], bias2s[1], bias2s[1]};
        dn0 = __builtin_amdgcn_mfma_f32_16x16x32_bf16(hb0, wb[0][0], dn0, 0, 0, 0);
        dn1 = __builtin_amdgcn_mfma_f32_16x16x32_bf16(hb0, wb[1][0], dn1, 0, 0, 0);
        dn0 = __builtin_amdgcn_mfma_f32_16x16x32_bf16(hb1, wb[0][1], dn0, 0, 0, 0);
        dn1 = __builtin_amdgcn_mfma_f32_16x16x32_bf16(hb1, wb[1][1], dn1, 0, 0, 0);

        if (nbase + 16 <= N) {
#pragma unroll
            for (int r = 0; r < 4; ++r) {
                float* dst = out + (size_t)(nbase + 4 * g + r) * 32 + el;
                dst[0]  = dn0[r];
                dst[16] = dn1[r];
            }
        } else {
#pragma unroll
            for (int r = 0; r < 4; ++r) {
                const int n = nbase + 4 * g + r;
                if (n < N) {
                    float* dst = out + (size_t)n * 32 + el;
                    dst[0]  = dn0[r];
                    dst[16] = dn1[r];
                }
            }
        }
    }
}

extern "C" void kernel_launch(void* const* d_in, const int* in_sizes, int n_in,
                              void* d_out, int out_size, void* d_ws, size_t ws_size,
                              hipStream_t stream) {
    const float* x     = (const float*)d_in[0];
    const int*   eidx  = (const int*)d_in[1];
    const float* eattr = (const float*)d_in[2];
    const float* u     = (const float*)d_in[3];
    const int*   batch = (const int*)d_in[4];
    const float* W1a   = (const float*)d_in[5];
    const float* b1a   = (const float*)d_in[6];
    const float* W1b   = (const float*)d_in[7];
    const float* b1b   = (const float*)d_in[8];
    const float* W2a   = (const float*)d_in[9];
    const float* b2a   = (const float*)d_in[10];
    const float* W2b   = (const float*)d_in[11];
    const float* b2b   = (const float*)d_in[12];
    float* out = (float*)d_out;

    const int N = in_sizes[0] / 32;
    const int E = in_sizes[1] / 2;
    const int* erow = eidx;
    const int* ecol = eidx + E;
    const int nb = (N + 255) / 256;

    // ws: sorted2 E*8 | binned E*8 | xbf N*64 | summed N*256 | counts N*4
    //   | rowstart (N+1)*4 | cursor N*4 | bucket_cursor 1KB | bsum 1KB
    const size_t need_full = (size_t)E * 16 + (size_t)N * 64 + (size_t)N * 256
                           + (size_t)(3 * N + 1) * 4 + 2048;

    if (ws_size >= need_full) {
        char* p = (char*)d_ws;
        int2*  sorted2  = (int2*)p;  p += (size_t)E * 8;
        int2*  binned   = (int2*)p;  p += (size_t)E * 8;
        unsigned short* xbf = (unsigned short*)p; p += (size_t)N * 64;
        float* summed   = (float*)p; p += (size_t)N * 256;
        int*   counts   = (int*)p;   p += (size_t)N * 4;
        int*   rowstart = (int*)p;   p += (size_t)(N + 1) * 4;
        int*   cursor   = (int*)p;   p += (size_t)N * 4;
        int*   bucket_cursor = (int*)p; p += 1024;
        int*   bsum     = (int*)p;

        hipMemsetAsync(summed, 0, (size_t)N * 256 + (size_t)N * 4, stream);
        count_rows_convx<<<1024, 256, 0, stream>>>(erow, counts, E, x, xbf, N * 4);
        scan_blocks<<<nb, 256, 0, stream>>>(counts, rowstart, bsum, N);
        scan_bsum<<<1, 256, 0, stream>>>(bsum, nb);
        scan_add<<<nb, 256, 0, stream>>>(rowstart, cursor, bucket_cursor,
                                         bsum, N, E);
        const int nbin = (E + BIN_CHUNK - 1) / BIN_CHUNK;
        bin_edges_v2<<<nbin, 256, 0, stream>>>(erow, ecol, bucket_cursor,
                                               binned, E);
        place_edges<<<512, 256, 0, stream>>>(binned, cursor, sorted2, E);
        edge_mlp_mfma<<<4096, 256, 0, stream>>>(xbf, sorted2, eattr,
                                                W1a, b1a, W1b, b1b, summed, E);
        node_mlp_mfma<<<784, 256, 0, stream>>>(x, summed, rowstart, u, batch,
                                               W2a, b2a, W2b, b2b, out, N);
    } else {
        // fallback: R19 small-ws path (xbf placed after fixed arrays; N*64
        // extra always fits since need_full is modest vs typical ws)
        char* p = (char*)d_ws;
        int2*  sorted2  = (int2*)p;  p += (size_t)E * 8;
        unsigned short* xbf = (unsigned short*)p; p += (size_t)N * 64;
        float* summed   = (float*)p; p += (size_t)N * 64 * 4;
        int*   counts   = (int*)p;   p += (size_t)N * 4;
        int*   rowstart = (int*)p;   p += (size_t)(N + 1) * 4;
        int*   cursor   = (int*)p;   p += (size_t)N * 4;
        int*   bucket_cursor = (int*)p; p += 1024;
        int*   bsum     = (int*)p;

        hipMemsetAsync(summed, 0, ((size_t)N * 64 + N) * sizeof(float), stream);
        count_rows_convx<<<1024, 256, 0, stream>>>(erow, counts, E, x, xbf, N * 4);
        scan_blocks<<<nb, 256, 0, stream>>>(counts, rowstart, bsum, N);
        scan_bsum<<<1, 256, 0, stream>>>(bsum, nb);
        scan_add<<<nb, 256, 0, stream>>>(rowstart, cursor, bucket_cursor,
                                         bsum, N, E);
        permute_edges<<<1024, 256, 0, stream>>>(erow, ecol, cursor, sorted2, E);
        edge_mlp_mfma<<<4096, 256, 0, stream>>>(xbf, sorted2, eattr,
                                                W1a, b1a, W1b, b1b, summed, E);
        node_mlp_mfma<<<784, 256, 0, stream>>>(x, summed, rowstart, u, batch,
                                               W2a, b2a, W2b, b2b, out, N);
    }
}